// Round 10
// baseline (65.983 us; speedup 1.0000x reference)
//
#include <hip/hip_runtime.h>
#include <hip/hip_fp16.h>

#define CIN 32
#define COUT 64
#define NB 4
#define NPTS 32768
#define KNN 16

typedef unsigned short u16;
typedef unsigned char u8;
typedef float f2v __attribute__((ext_vector_type(2)));
typedef float f4v __attribute__((ext_vector_type(4)));
typedef int i4v __attribute__((ext_vector_type(4)));
typedef unsigned int u4v __attribute__((ext_vector_type(4)));
typedef unsigned int u2v __attribute__((ext_vector_type(2)));

__device__ __forceinline__ u16 f2h(float f) {
  _Float16 h = (_Float16)f;
  u16 u; __builtin_memcpy(&u, &h, 2); return u;
}
__device__ __forceinline__ f2v h2_to_f2(unsigned int u) {
  _Float16 a, b;
  __builtin_memcpy(&a, (const char*)&u, 2);
  __builtin_memcpy(&b, ((const char*)&u) + 2, 2);
  return (f2v){(float)a, (float)b};
}

// Kernel 1: pure GEMM + store, all CACHED (NT store here was the R8
// regression: wave-strided 16B stores need L2 line-merging). lt fp16,
// et fp8 e4m3, both (B,N,64).
__global__ __launch_bounds__(256) void k1_gemm(
    const float* __restrict__ feat, const float* __restrict__ W1,
    const float* __restrict__ W2, u16* __restrict__ lt, u8* __restrict__ et) {
  const int bid = blockIdx.x;
  const int b = bid >> 9;
  const int n0 = (bid & 511) << 6;
  const int t = threadIdx.x;
  const int lane = t & 63;
  const int wchunk = __builtin_amdgcn_readfirstlane(t >> 6);
  const int n = n0 + lane;

  f2v fv[16];
  const float* fp = feat + (size_t)b * CIN * NPTS + n;
#pragma unroll
  for (int c2 = 0; c2 < 16; ++c2)
    fv[c2] = (f2v){fp[(size_t)(2 * c2) * NPTS], fp[(size_t)(2 * c2 + 1) * NPTS]};

  const int half = wchunk >> 1;        // 0 -> W1 (local fp16), 1 -> W2 (edge fp8)
  const int rbase = (wchunk & 1) * 32;
  const float* Wp = half ? W2 : W1;

  unsigned int pkh[16];
  unsigned int pk8[8];

#pragma unroll
  for (int oo = 0; oo < 32; oo += 4) {
    const float* w0 = Wp + (size_t)(rbase + oo) * CIN;
    const f2v* wr0 = reinterpret_cast<const f2v*>(w0);
    const f2v* wr1 = reinterpret_cast<const f2v*>(w0 + CIN);
    const f2v* wr2 = reinterpret_cast<const f2v*>(w0 + 2 * CIN);
    const f2v* wr3 = reinterpret_cast<const f2v*>(w0 + 3 * CIN);
    f2v p0 = (f2v)0.f, p1 = (f2v)0.f, p2 = (f2v)0.f, p3 = (f2v)0.f;
#pragma unroll
    for (int c2 = 0; c2 < 16; ++c2) {
      const f2v fc = fv[c2];
      p0 = __builtin_elementwise_fma(wr0[c2], fc, p0);
      p1 = __builtin_elementwise_fma(wr1[c2], fc, p1);
      p2 = __builtin_elementwise_fma(wr2[c2], fc, p2);
      p3 = __builtin_elementwise_fma(wr3[c2], fc, p3);
    }
    const float a0 = p0.x + p0.y, a1 = p1.x + p1.y;
    const float a2 = p2.x + p2.y, a3 = p3.x + p3.y;
    if (half == 0) {
      pkh[oo / 2]     = (unsigned)f2h(a0) | ((unsigned)f2h(a1) << 16);
      pkh[oo / 2 + 1] = (unsigned)f2h(a2) | ((unsigned)f2h(a3) << 16);
    } else {
      int u = 0;
      u = __builtin_amdgcn_cvt_pk_fp8_f32(a0, a1, u, false);
      u = __builtin_amdgcn_cvt_pk_fp8_f32(a2, a3, u, true);
      pk8[oo / 4] = (unsigned)u;
    }
  }
  if (half == 0) {
    u4v* dp = reinterpret_cast<u4v*>(lt + ((size_t)(b * NPTS + n)) * COUT + rbase);
#pragma unroll
    for (int q = 0; q < 4; ++q)
      dp[q] = (u4v){pkh[4 * q], pkh[4 * q + 1], pkh[4 * q + 2], pkh[4 * q + 3]};
  } else {
    u4v* dp = reinterpret_cast<u4v*>(et + ((size_t)(b * NPTS + n)) * COUT + rbase);
    dp[0] = (u4v){pk8[0], pk8[1], pk8[2], pk8[3]};
    dp[1] = (u4v){pk8[4], pk8[5], pk8[6], pk8[7]};
  }
}

// Kernel 2: full output, tile-pipelined persistent blocks. Grid = 1024
// blocks (= 4/CU, all resident). Each block owns 128 n = 4 tiles x 32 n.
// Per tile, the per-thread shape is R8's proven one (lane = nn*8+cg,
// 1 n/thread, 16x 8B fp8 gathers; 8 cg lanes cover one 64B row). The NT
// knn/lt loads for tile t+1 are issued while tile t's gathers/compute/
// write run -> knn latency off the critical path, no VGPR blowup.
// BN constants hoisted. Cached gathers; NT knn/lt loads; NT out stores.
__global__ __launch_bounds__(256) void k2_gather(
    const u16* __restrict__ lt, const u8* __restrict__ et,
    const int* __restrict__ knn, const float* __restrict__ gamma,
    const float* __restrict__ beta, const float* __restrict__ mean,
    const float* __restrict__ var, float* __restrict__ out) {
  __shared__ float obuf[128 * 33];
  int bid = blockIdx.x;
  bid = (bid & 7) * 128 + (bid >> 3);   // 1024 % 8 == 0 -> bijective
  const int b = bid >> 8;               // 256 blocks per batch
  const int nbase = (bid & 255) << 7;   // 128 n per block
  const int t = threadIdx.x;
  const int w = t >> 6;
  const int lane = t & 63;
  const int nn = lane >> 3;   // 0..7
  const int cg = lane & 7;    // 0..7
  const int ch = cg * 8;
  const int col = w * 8 + nn; // 0..31 within tile

  const size_t rowbase = (size_t)b * NPTS;
  const u8* etb = et + rowbase * COUT + ch;

  // hoisted BN constants (channels ch..ch+7 central, 64+ch..64+ch+7 diff)
  f2v ivc[4], shc[4], inv2[4], sh2[4];
#pragma unroll
  for (int i = 0; i < 4; ++i) {
    {
      const int r0 = ch + 2 * i;
      const float iv0 = gamma[r0] * rsqrtf(var[r0] + 1e-5f);
      const float iv1 = gamma[r0 + 1] * rsqrtf(var[r0 + 1] + 1e-5f);
      ivc[i] = (f2v){iv0, iv1};
      shc[i] = (f2v){beta[r0] - mean[r0] * iv0, beta[r0 + 1] - mean[r0 + 1] * iv1};
    }
    {
      const int r0 = 64 + ch + 2 * i;
      const float iv0 = gamma[r0] * rsqrtf(var[r0] + 1e-5f);
      const float iv1 = gamma[r0 + 1] * rsqrtf(var[r0 + 1] + 1e-5f);
      inv2[i] = (f2v){iv0, iv1};
      sh2[i] = (f2v){beta[r0] - mean[r0] * iv0, beta[r0 + 1] - mean[r0 + 1] * iv1};
    }
  }

  i4v kv[2][4];
  u4v lv[2];
  {  // prologue: tile 0 loads
    const int n = nbase + col;
    const i4v* kp = reinterpret_cast<const i4v*>(knn + (rowbase + n) * KNN);
    kv[0][0] = __builtin_nontemporal_load(kp);
    kv[0][1] = __builtin_nontemporal_load(kp + 1);
    kv[0][2] = __builtin_nontemporal_load(kp + 2);
    kv[0][3] = __builtin_nontemporal_load(kp + 3);
    lv[0] = __builtin_nontemporal_load(
        reinterpret_cast<const u4v*>(lt + (rowbase + n) * COUT + ch));
  }

  const f2v zero = (f2v)0.f;
#pragma unroll
  for (int tt_ = 0; tt_ < 4; ++tt_) {
    const int cur = tt_ & 1, nxt = cur ^ 1;
    // gathers for this tile
    const int idx[16] = {kv[cur][0].x, kv[cur][0].y, kv[cur][0].z, kv[cur][0].w,
                         kv[cur][1].x, kv[cur][1].y, kv[cur][1].z, kv[cur][1].w,
                         kv[cur][2].x, kv[cur][2].y, kv[cur][2].z, kv[cur][2].w,
                         kv[cur][3].x, kv[cur][3].y, kv[cur][3].z, kv[cur][3].w};
    u2v e[16];
#pragma unroll
    for (int k = 0; k < 16; ++k)
      e[k] = *reinterpret_cast<const u2v*>(etb + ((size_t)(unsigned)idx[k] << 6));

    // issue next tile's knn/lt while gathers are in flight
    if (tt_ < 3) {
      const int n2 = nbase + (tt_ + 1) * 32 + col;
      const i4v* kp2 = reinterpret_cast<const i4v*>(knn + (rowbase + n2) * KNN);
      kv[nxt][0] = __builtin_nontemporal_load(kp2);
      kv[nxt][1] = __builtin_nontemporal_load(kp2 + 1);
      kv[nxt][2] = __builtin_nontemporal_load(kp2 + 2);
      kv[nxt][3] = __builtin_nontemporal_load(kp2 + 3);
      lv[nxt] = __builtin_nontemporal_load(
          reinterpret_cast<const u4v*>(lt + (rowbase + n2) * COUT + ch));
    }

    // central half + tt consts from this tile's local row (hides gather wait)
    const unsigned int lw[4] = {lv[cur].x, lv[cur].y, lv[cur].z, lv[cur].w};
    f2v ttc[4];
#pragma unroll
    for (int i = 0; i < 4; ++i) {
      const f2v l = h2_to_f2(lw[i]);
      const f2v cen = __builtin_elementwise_max(
          __builtin_elementwise_fma(l, ivc[i], shc[i]), zero);
      obuf[(ch + 2 * i) * 33 + col] = cen.x;
      obuf[(ch + 2 * i + 1) * 33 + col] = cen.y;
      ttc[i] = sh2[i] - l * inv2[i];
    }

    f2v acc[4] = {zero, zero, zero, zero};
#pragma unroll
    for (int k = 0; k < 16; ++k) {
      const f2v d0 = __builtin_amdgcn_cvt_pk_f32_fp8(e[k].x, false);
      const f2v d1 = __builtin_amdgcn_cvt_pk_f32_fp8(e[k].x, true);
      const f2v d2 = __builtin_amdgcn_cvt_pk_f32_fp8(e[k].y, false);
      const f2v d3 = __builtin_amdgcn_cvt_pk_f32_fp8(e[k].y, true);
      acc[0] += __builtin_elementwise_max(__builtin_elementwise_fma(d0, inv2[0], ttc[0]), zero);
      acc[1] += __builtin_elementwise_max(__builtin_elementwise_fma(d1, inv2[1], ttc[1]), zero);
      acc[2] += __builtin_elementwise_max(__builtin_elementwise_fma(d2, inv2[2], ttc[2]), zero);
      acc[3] += __builtin_elementwise_max(__builtin_elementwise_fma(d3, inv2[3], ttc[3]), zero);
    }
#pragma unroll
    for (int i = 0; i < 4; ++i) {
      const int r0 = 64 + ch + 2 * i;
      obuf[r0 * 33 + col] = acc[i].x * 0.0625f;
      obuf[(r0 + 1) * 33 + col] = acc[i].y * 0.0625f;
    }
    __syncthreads();
    // write this tile: 128 ch x 32 n, coalesced f4v NT stores
    const int n0t = nbase + tt_ * 32;
#pragma unroll
    for (int r = 0; r < 4; ++r) {
      const int c = r * 32 + (t >> 3);
      const int n4 = (t & 7) * 4;
      const f4v v = {obuf[c * 33 + n4], obuf[c * 33 + n4 + 1],
                     obuf[c * 33 + n4 + 2], obuf[c * 33 + n4 + 3]};
      __builtin_nontemporal_store(
          v, reinterpret_cast<f4v*>(out + ((size_t)b * 128 + c) * NPTS + n0t + n4));
    }
    if (tt_ < 3) __syncthreads();  // obuf reuse guard
  }
}

extern "C" void kernel_launch(void* const* d_in, const int* in_sizes, int n_in,
                              void* d_out, int out_size, void* d_ws, size_t ws_size,
                              hipStream_t stream) {
  const float* feat  = (const float*)d_in[0];
  const int*   knn   = (const int*)d_in[1];
  const float* W1    = (const float*)d_in[2];
  const float* W2    = (const float*)d_in[3];
  const float* gamma = (const float*)d_in[4];
  const float* beta  = (const float*)d_in[5];
  const float* mean  = (const float*)d_in[6];
  const float* var   = (const float*)d_in[7];
  float* out = (float*)d_out;

  u16* lt = (u16*)d_ws;                           // (B,N,64) fp16 local, 16.8 MB
  u8* et = (u8*)(lt + (size_t)NB * NPTS * COUT);  // (B,N,64) fp8 edge, 8.4 MB

  k1_gemm<<<dim3(NB * NPTS / 64), 256, 0, stream>>>(feat, W1, W2, lt, et);
  k2_gather<<<dim3(NB * NPTS / 128), 256, 0, stream>>>(lt, et, knn, gamma, beta,
                                                       mean, var, out);
}